// Round 8
// baseline (188.503 us; speedup 1.0000x reference)
//
#include <hip/hip_runtime.h>

// TwoTwoNet: rank-2 recurrence collapse, round 7.
// R6 finding: 466 cyc/step = ~294 issue + ~172 dep-stall; 1 wave/SIMD has
// nothing to fill stalls. KEY: channel tables (d,e,g1,g2,wo) are
// batch-INDEPENDENT -> one wave runs TWO batch chains off the same tables,
// interleaved, so chain A's stalls are filled by chain B's issue.
// Also: alpha-fold dropped (no copysign/rcp serial head; med3 bounds are the
// inline consts -1.0/1.0), W folded into tables g1,g2 so the reduce directly
// yields q1 = w00*Sd + w01*Se. One asm block does all 6 DPP reduce chains
// interleaved 6-apart (covers DPP hazards by construction) + 6 readlanes.
// Math: alpha_t = q1_{t-1} + x_t*A1, beta_t = q2_{t-1} + x_t*A2,
//       m = clip(alpha*d + beta*e, -1, 1)  (per channel)
//       q1' = <m, g1>, q2' = <m, g2>, out_t = <m, wo>.

typedef float f32x2 __attribute__((ext_vector_type(2)));

constexpr int Bc = 256;
constexpr int Tc = 512;
constexpr int CH = Tc / 64;   // 8 chunks of 64 steps

__device__ __forceinline__ float readlane_f(float v, int l) {
    return __int_as_float(__builtin_amdgcn_readlane(__float_as_int(v), l));
}

// 6 interleaved 64-lane sums via DPP; totals -> lane 63 -> SGPRs.
#define DPP6(lvl, msk)                                                                              \
        "v_add_f32_dpp %[a], %[a], %[a] " lvl " row_mask:" msk " bank_mask:0xf bound_ctrl:1\n\t"    \
        "v_add_f32_dpp %[b], %[b], %[b] " lvl " row_mask:" msk " bank_mask:0xf bound_ctrl:1\n\t"    \
        "v_add_f32_dpp %[c], %[c], %[c] " lvl " row_mask:" msk " bank_mask:0xf bound_ctrl:1\n\t"    \
        "v_add_f32_dpp %[d], %[d], %[d] " lvl " row_mask:" msk " bank_mask:0xf bound_ctrl:1\n\t"    \
        "v_add_f32_dpp %[e], %[e], %[e] " lvl " row_mask:" msk " bank_mask:0xf bound_ctrl:1\n\t"    \
        "v_add_f32_dpp %[f], %[f], %[f] " lvl " row_mask:" msk " bank_mask:0xf bound_ctrl:1\n\t"

#define WAVE_REDUCE6_READ(h1, h2, h3, h4, h5, h6, s1, s2, s3, s4, s5, s6)                           \
    asm("s_nop 1\n\t"                                                                               \
        DPP6("row_shr:1",   "0xf")                                                                  \
        DPP6("row_shr:2",   "0xf")                                                                  \
        DPP6("row_shr:4",   "0xf")                                                                  \
        DPP6("row_shr:8",   "0xf")                                                                  \
        DPP6("row_bcast:15","0xa")                                                                  \
        DPP6("row_bcast:31","0xc")                                                                  \
        "v_readlane_b32 %[x], %[a], 63\n\t"                                                         \
        "v_readlane_b32 %[y], %[b], 63\n\t"                                                         \
        "v_readlane_b32 %[z], %[c], 63\n\t"                                                         \
        "v_readlane_b32 %[u], %[d], 63\n\t"                                                         \
        "v_readlane_b32 %[v], %[e], 63\n\t"                                                         \
        "v_readlane_b32 %[w], %[f], 63"                                                             \
        : [a] "+v"(h1), [b] "+v"(h2), [c] "+v"(h3),                                                 \
          [d] "+v"(h4), [e] "+v"(h5), [f] "+v"(h6),                                                 \
          [x] "=s"(s1), [y] "=s"(s2), [z] "=s"(s3),                                                 \
          [u] "=s"(s4), [v] "=s"(s5), [w] "=s"(s6))

#define DECL_TBL(i) f32x2 d2_##i, e2_##i, g1_##i, g2_##i, wo_##i

#define INIT_TBL(i) do { \
    _Pragma("unroll") \
    for (int h = 0; h < 2; ++h) { \
        const int c = lane + 64 * (2 * (i) + h); \
        const float dv   = dec_orth[c]; \
        const float ev   = enc_orth[c]; \
        const float mv   = mask[c]; \
        const float encv = encoder[c]; \
        const float decv = decoder[c]; \
        const float s0v  = state0[c]; \
        const float mdv = mv * dv, mev = mv * ev; \
        d2_##i[h]  = dv;  e2_##i[h]  = ev; \
        g1_##i[h] = fmaf(w00, mdv, w01 * mev); \
        g2_##i[h] = fmaf(w10, mdv, w11 * mev); \
        wo_##i[h] = mv * decv; \
        s0d += s0v * dv;  s0e += s0v * ev; \
        kd = fmaf(mv * encv, dv, kd); \
        ke = fmaf(mv * encv, ev, ke); \
    } \
} while (0)

// One channel-pair, one batch: 7 ops (pk_mul, pk_fma, 2x med3, 3x pk_fma).
#define ACC_J(i, al, be, A1V, A2V, AOV) do { \
    f32x2 tt = (al) * d2_##i + (be) * e2_##i; \
    f32x2 mm; \
    mm.x = __builtin_amdgcn_fmed3f(tt.x, -1.0f, 1.0f); \
    mm.y = __builtin_amdgcn_fmed3f(tt.y, -1.0f, 1.0f); \
    A1V += mm * g1_##i; \
    A2V += mm * g2_##i; \
    AOV += mm * wo_##i; \
} while (0)

__global__ __attribute__((amdgpu_waves_per_eu(1, 1))) __launch_bounds__(64)
void twotwonet_kernel(
    const float* __restrict__ x,        // [B, T]
    const float* __restrict__ state0,   // [n]
    const float* __restrict__ mask,     // [n]
    const float* __restrict__ w,        // [2,2]
    const float* __restrict__ dec_orth, // [n]
    const float* __restrict__ enc_orth, // [n]
    const float* __restrict__ decoder,  // [n]
    const float* __restrict__ encoder,  // [n]
    float* __restrict__ out)            // [B, T]
{
    const int b0   = 2 * blockIdx.x;     // this wave runs batches b0, b0+1
    const int lane = threadIdx.x;        // 0..63

    const float w00 = w[0], w01 = w[1], w10 = w[2], w11 = w[3];

    DECL_TBL(0); DECL_TBL(1); DECL_TBL(2); DECL_TBL(3);
    DECL_TBL(4); DECL_TBL(5); DECL_TBL(6); DECL_TBL(7);

    float s0d = 0.f, s0e = 0.f, kd = 0.f, ke = 0.f;
    INIT_TBL(0); INIT_TBL(1); INIT_TBL(2); INIT_TBL(3);
    INIT_TBL(4); INIT_TBL(5); INIT_TBL(6); INIT_TBL(7);

    // cold-path init reduce (runs once)
#pragma unroll
    for (int m = 32; m >= 1; m >>= 1) {
        s0d += __shfl_xor(s0d, m, 64);
        s0e += __shfl_xor(s0e, m, 64);
        kd  += __shfl_xor(kd, m, 64);
        ke  += __shfl_xor(ke, m, 64);
    }

    const float A1 = fmaf(w00, kd, w01 * ke);   // x-coupling for alpha
    const float A2 = fmaf(w10, kd, w11 * ke);   // x-coupling for beta

    // Preload both batches' x rows: 8 regs each.
    const float* xrowA = x + (size_t)b0 * Tc;
    const float* xrowB = x + (size_t)(b0 + 1) * Tc;
    float xrA[CH], xrB[CH];
#pragma unroll
    for (int c = 0; c < CH; ++c) { xrA[c] = xrowA[lane + 64 * c]; xrB[c] = xrowB[lane + 64 * c]; }

    // Carried state per batch (wave-uniform): q1 = w00*Sd + w01*Se, q2 = ...
    float q1A = fmaf(w00, s0d, w01 * s0e);
    float q2A = fmaf(w10, s0d, w11 * s0e);
    float q1B = q1A, q2B = q2A;

#pragma unroll
    for (int c = 0; c < CH; ++c) {
        float obufA = 0.f, obufB = 0.f;
#pragma unroll 2
        for (int t2 = 0; t2 < 64; ++t2) {
            const float xsA = readlane_f(xrA[c], t2);
            const float xsB = readlane_f(xrB[c], t2);

            const float alA = fmaf(xsA, A1, q1A);
            const float beA = fmaf(xsA, A2, q2A);
            const float alB = fmaf(xsB, A1, q1B);
            const float beB = fmaf(xsB, A2, q2B);
            const f32x2 a2A = {alA, alA}, b2A = {beA, beA};
            const f32x2 a2B = {alB, alB}, b2B = {beB, beB};

            f32x2 p1A = {0.f, 0.f}, p2A = {0.f, 0.f}, poA = {0.f, 0.f};
            f32x2 p1B = {0.f, 0.f}, p2B = {0.f, 0.f}, poB = {0.f, 0.f};
            // interleave A and B pairs: B's ops fill A's dep-latency slots
            ACC_J(0, a2A, b2A, p1A, p2A, poA);  ACC_J(0, a2B, b2B, p1B, p2B, poB);
            ACC_J(1, a2A, b2A, p1A, p2A, poA);  ACC_J(1, a2B, b2B, p1B, p2B, poB);
            ACC_J(2, a2A, b2A, p1A, p2A, poA);  ACC_J(2, a2B, b2B, p1B, p2B, poB);
            ACC_J(3, a2A, b2A, p1A, p2A, poA);  ACC_J(3, a2B, b2B, p1B, p2B, poB);
            ACC_J(4, a2A, b2A, p1A, p2A, poA);  ACC_J(4, a2B, b2B, p1B, p2B, poB);
            ACC_J(5, a2A, b2A, p1A, p2A, poA);  ACC_J(5, a2B, b2B, p1B, p2B, poB);
            ACC_J(6, a2A, b2A, p1A, p2A, poA);  ACC_J(6, a2B, b2B, p1B, p2B, poB);
            ACC_J(7, a2A, b2A, p1A, p2A, poA);  ACC_J(7, a2B, b2B, p1B, p2B, poB);

            float h1A = p1A.x + p1A.y, h2A = p2A.x + p2A.y, hoA = poA.x + poA.y;
            float h1B = p1B.x + p1B.y, h2B = p2B.x + p2B.y, hoB = poB.x + poB.y;

            float r1A, r2A, roA, r1B, r2B, roB;
            WAVE_REDUCE6_READ(h1A, h2A, hoA, h1B, h2B, hoB,
                              r1A, r2A, roA, r1B, r2B, roB);
            q1A = r1A; q2A = r2A;
            q1B = r1B; q2B = r2B;

            const bool mine = (t2 == lane);
            obufA = mine ? roA : obufA;
            obufB = mine ? roB : obufB;
        }
        out[(size_t)b0 * Tc + 64 * c + lane]       = obufA;
        out[(size_t)(b0 + 1) * Tc + 64 * c + lane] = obufB;
    }
}

extern "C" void kernel_launch(void* const* d_in, const int* in_sizes, int n_in,
                              void* d_out, int out_size, void* d_ws, size_t ws_size,
                              hipStream_t stream) {
    const float* x        = (const float*)d_in[0];
    const float* state0   = (const float*)d_in[1];
    const float* mask     = (const float*)d_in[2];
    const float* w        = (const float*)d_in[3];
    const float* dec_orth = (const float*)d_in[4];
    const float* enc_orth = (const float*)d_in[5];
    const float* decoder  = (const float*)d_in[6];
    const float* encoder  = (const float*)d_in[7];
    float* out = (float*)d_out;

    twotwonet_kernel<<<dim3(Bc / 2), dim3(64), 0, stream>>>(
        x, state0, mask, w, dec_orth, enc_orth, decoder, encoder, out);
}

// Round 9
// 117.859 us; speedup vs baseline: 1.5994x; 1.5994x over previous
//
#include <hip/hip_runtime.h>

// TwoTwoNet: rank-2 recurrence collapse, round 8.
// R7 lesson: ILP within one wave is unwinnable (register-pressure scheduler
// serializes). New structure: ONE BATCH PER BLOCK, 4 waves (4 SIMDs of one CU)
// each owning a 256-channel slice (4 ch/lane -> ~20 table floats, no pressure).
// Per step: 14-instr inner, 3-chain DPP reduce to lane 63, lane-63 LDS write,
// one barrier, broadcast f32x4 reads, 6 packed adds -> (q1,q2,out).
// Double-buffered partial slots => single barrier per step is race-free:
// write(k+1) goes to the other buffer; reaching barrier(k+1) implies read(k)
// retired (program order), so reuse at k+2 is safe.
// Math (verified R3-R7): alpha_t = q1 + x_t*A1, beta_t = q2 + x_t*A2,
// m = clip(alpha*d + beta*e, -1, 1); q1' = <m,g1>, q2' = <m,g2>, out = <m,wo>
// with g1 = w00*mask*d + w01*mask*e, g2 = w10*mask*d + w11*mask*e (W folded).

typedef float f32x2 __attribute__((ext_vector_type(2)));
typedef float f32x4 __attribute__((ext_vector_type(4)));

constexpr int Bc = 256;
constexpr int Tc = 512;
constexpr int CH = Tc / 64;   // 8 chunks of 64 steps

// 3 interleaved 64-lane sums via DPP; totals land in lane 63 (no readlane —
// lane 63 is also the LDS writer). Interleave-3 covers DPP wait states.
#define DPP3(lvl, msk)                                                                              \
        "v_add_f32_dpp %[a], %[a], %[a] " lvl " row_mask:" msk " bank_mask:0xf bound_ctrl:1\n\t"    \
        "v_add_f32_dpp %[b], %[b], %[b] " lvl " row_mask:" msk " bank_mask:0xf bound_ctrl:1\n\t"    \
        "v_add_f32_dpp %[c], %[c], %[c] " lvl " row_mask:" msk " bank_mask:0xf bound_ctrl:1\n\t"

#define WAVE_REDUCE3_63(h1, h2, h3)                                                                 \
    asm("s_nop 1\n\t"                                                                               \
        DPP3("row_shr:1",   "0xf")                                                                  \
        DPP3("row_shr:2",   "0xf")                                                                  \
        DPP3("row_shr:4",   "0xf")                                                                  \
        DPP3("row_shr:8",   "0xf")                                                                  \
        DPP3("row_bcast:15","0xa")                                                                  \
        DPP3("row_bcast:31","0xc")                                                                  \
        "s_nop 1"                                                                                   \
        : [a] "+v"(h1), [b] "+v"(h2), [c] "+v"(h3))

__global__ __launch_bounds__(256) void twotwonet_kernel(
    const float* __restrict__ x,        // [B, T]
    const float* __restrict__ state0,   // [n]
    const float* __restrict__ mask,     // [n]
    const float* __restrict__ w,        // [2,2]
    const float* __restrict__ dec_orth, // [n]
    const float* __restrict__ enc_orth, // [n]
    const float* __restrict__ decoder,  // [n]
    const float* __restrict__ encoder,  // [n]
    float* __restrict__ out)            // [B, T]
{
    const int b    = blockIdx.x;
    const int tid  = threadIdx.x;
    const int wave = tid >> 6;
    const int lane = tid & 63;

    __shared__ f32x4 parts[2][4];   // [buffer][wave] = {q1,q2,out,pad}
    __shared__ f32x4 initp[4];      // one-time init partials

    const float w00 = w[0], w01 = w[1], w10 = w[2], w11 = w[3];

    // This wave's 256-channel slice: c = wave*256 + lane + 64*(2j+h), j=0..1
    f32x2 d2[2], e2[2], g1[2], g2[2], wo[2];
    float s0d = 0.f, s0e = 0.f, kd = 0.f, ke = 0.f;
#pragma unroll
    for (int j = 0; j < 2; ++j) {
#pragma unroll
        for (int h = 0; h < 2; ++h) {
            const int c = wave * 256 + lane + 64 * (2 * j + h);
            const float dv   = dec_orth[c];
            const float ev   = enc_orth[c];
            const float mv   = mask[c];
            const float encv = encoder[c];
            const float decv = decoder[c];
            const float s0v  = state0[c];
            const float mdv = mv * dv, mev = mv * ev;
            d2[j][h] = dv;  e2[j][h] = ev;
            g1[j][h] = fmaf(w00, mdv, w01 * mev);
            g2[j][h] = fmaf(w10, mdv, w11 * mev);
            wo[j][h] = mv * decv;
            s0d += s0v * dv;  s0e += s0v * ev;
            kd = fmaf(mv * encv, dv, kd);
            ke = fmaf(mv * encv, ev, ke);
        }
    }
    // One-time cross-wave init reduce (shfl within wave, LDS across waves).
#pragma unroll
    for (int m = 32; m >= 1; m >>= 1) {
        s0d += __shfl_xor(s0d, m, 64);
        s0e += __shfl_xor(s0e, m, 64);
        kd  += __shfl_xor(kd, m, 64);
        ke  += __shfl_xor(ke, m, 64);
    }
    if (lane == 0) initp[wave] = (f32x4){s0d, s0e, kd, ke};
    __syncthreads();
    {
        const f32x4 tot = (initp[0] + initp[1]) + (initp[2] + initp[3]);
        s0d = tot.x; s0e = tot.y; kd = tot.z; ke = tot.w;
    }

    const float A1 = fmaf(w00, kd, w01 * ke);
    const float A2 = fmaf(w10, kd, w11 * ke);

    // Every wave preloads the full x row (readlane is wave-local): 8 regs.
    const float* xrow = x + (size_t)b * Tc;
    float xr[CH];
#pragma unroll
    for (int c = 0; c < CH; ++c) xr[c] = xrow[lane + 64 * c];

    float q1 = fmaf(w00, s0d, w01 * s0e);
    float q2 = fmaf(w10, s0d, w11 * s0e);

#pragma unroll
    for (int c = 0; c < CH; ++c) {
        float obuf = 0.f;
#pragma unroll 2
        for (int t2 = 0; t2 < 64; ++t2) {
            const int pb = t2 & 1;   // static under unroll-2
            const float xs = __int_as_float(
                __builtin_amdgcn_readlane(__float_as_int(xr[c]), t2));

            const float al = fmaf(xs, A1, q1);
            const float be = fmaf(xs, A2, q2);
            const f32x2 a2 = {al, al}, b2 = {be, be};

            f32x2 p1 = {0.f, 0.f}, p2 = {0.f, 0.f}, po = {0.f, 0.f};
#pragma unroll
            for (int j = 0; j < 2; ++j) {
                f32x2 tt = a2 * d2[j] + b2 * e2[j];   // pk_mul + pk_fma
                f32x2 mm;
                mm.x = __builtin_amdgcn_fmed3f(tt.x, -1.0f, 1.0f);
                mm.y = __builtin_amdgcn_fmed3f(tt.y, -1.0f, 1.0f);
                p1 += mm * g1[j];
                p2 += mm * g2[j];
                po += mm * wo[j];
            }
            float h1 = p1.x + p1.y;
            float h2 = p2.x + p2.y;
            float ho = po.x + po.y;

            WAVE_REDUCE3_63(h1, h2, ho);

            if (lane == 63) parts[pb][wave] = (f32x4){h1, h2, ho, 0.f};
            __syncthreads();   // lgkmcnt(0) + s_barrier

            const f32x4 s = (parts[pb][0] + parts[pb][1])
                          + (parts[pb][2] + parts[pb][3]);
            q1 = s.x;
            q2 = s.y;
            obuf = (t2 == lane) ? s.z : obuf;   // only wave 0's copy is stored
        }
        if (wave == 0) out[(size_t)b * Tc + 64 * c + lane] = obuf;
    }
}

extern "C" void kernel_launch(void* const* d_in, const int* in_sizes, int n_in,
                              void* d_out, int out_size, void* d_ws, size_t ws_size,
                              hipStream_t stream) {
    const float* x        = (const float*)d_in[0];
    const float* state0   = (const float*)d_in[1];
    const float* mask     = (const float*)d_in[2];
    const float* w        = (const float*)d_in[3];
    const float* dec_orth = (const float*)d_in[4];
    const float* enc_orth = (const float*)d_in[5];
    const float* decoder  = (const float*)d_in[6];
    const float* encoder  = (const float*)d_in[7];
    float* out = (float*)d_out;

    twotwonet_kernel<<<dim3(Bc), dim3(256), 0, stream>>>(
        x, state0, mask, w, dec_orth, enc_orth, decoder, encoder, out);
}

// Round 11
// 101.168 us; speedup vs baseline: 1.8633x; 1.1650x over previous
//
#include <hip/hip_runtime.h>

// TwoTwoNet: rank-2 recurrence collapse, round 10 (R9 compile fix).
// Structure = R6 (1 wave/batch, 16ch/lane tables, waves_per_eu(1,1), asm DPP
// reduce) + forced v_pk_fma_f32/v_pk_mul_f32 inner loop. VOP3P f32 ops need
// 64-bit pair operands for ALL sources -> broadcast al/be into {al,al},{be,be}
// once per step (4 movs amortized over 8 channel pairs).
// Math: alpha_t = q1 + x_t*A1, beta_t = q2 + x_t*A2,
//       m = clip(alpha*d + beta*e, -1, 1)
//       q1' = <m,g1>, q2' = <m,g2>, out_t = <m,wo>
// with g1 = w00*mask*d + w01*mask*e, g2 = w10*mask*d + w11*mask*e.

typedef float f32x2 __attribute__((ext_vector_type(2)));

constexpr int Bc = 256;
constexpr int Tc = 512;
constexpr int CH = Tc / 64;   // 8 chunks of 64 steps

__device__ __forceinline__ float readlane_f(float v, int l) {
    return __int_as_float(__builtin_amdgcn_readlane(__float_as_int(v), l));
}

__device__ __forceinline__ f32x2 pk_fma(f32x2 a, f32x2 b, f32x2 c) {
    f32x2 d;
    asm("v_pk_fma_f32 %0, %1, %2, %3" : "=v"(d) : "v"(a), "v"(b), "v"(c));
    return d;
}
__device__ __forceinline__ f32x2 pk_mul(f32x2 a, f32x2 b) {
    f32x2 d;
    asm("v_pk_mul_f32 %0, %1, %2" : "=v"(d) : "v"(a), "v"(b));
    return d;
}

// 3 interleaved 64-lane sums via DPP; totals -> lane 63 -> SGPRs.
#define DPP3(lvl, msk)                                                                              \
        "v_add_f32_dpp %[a], %[a], %[a] " lvl " row_mask:" msk " bank_mask:0xf bound_ctrl:1\n\t"    \
        "v_add_f32_dpp %[b], %[b], %[b] " lvl " row_mask:" msk " bank_mask:0xf bound_ctrl:1\n\t"    \
        "v_add_f32_dpp %[c], %[c], %[c] " lvl " row_mask:" msk " bank_mask:0xf bound_ctrl:1\n\t"

#define WAVE_REDUCE3_READ(h1, h2, h3, s1, s2, s3)                                                   \
    asm("s_nop 1\n\t"                                                                               \
        DPP3("row_shr:1",   "0xf")                                                                  \
        DPP3("row_shr:2",   "0xf")                                                                  \
        DPP3("row_shr:4",   "0xf")                                                                  \
        DPP3("row_shr:8",   "0xf")                                                                  \
        DPP3("row_bcast:15","0xa")                                                                  \
        DPP3("row_bcast:31","0xc")                                                                  \
        "v_readlane_b32 %[x], %[a], 63\n\t"                                                         \
        "v_readlane_b32 %[y], %[b], 63\n\t"                                                         \
        "v_readlane_b32 %[z], %[c], 63"                                                             \
        : [a] "+v"(h1), [b] "+v"(h2), [c] "+v"(h3),                                                 \
          [x] "=s"(s1), [y] "=s"(s2), [z] "=s"(s3))

#define DECL_TBL(i) f32x2 d2_##i, e2_##i, g1_##i, g2_##i, wo_##i

#define INIT_TBL(i) do { \
    _Pragma("unroll") \
    for (int h = 0; h < 2; ++h) { \
        const int c = lane + 64 * (2 * (i) + h); \
        const float dv   = dec_orth[c]; \
        const float ev   = enc_orth[c]; \
        const float mv   = mask[c]; \
        const float encv = encoder[c]; \
        const float decv = decoder[c]; \
        const float s0v  = state0[c]; \
        const float mdv = mv * dv, mev = mv * ev; \
        d2_##i[h]  = dv;  e2_##i[h]  = ev; \
        g1_##i[h] = fmaf(w00, mdv, w01 * mev); \
        g2_##i[h] = fmaf(w10, mdv, w11 * mev); \
        wo_##i[h] = mv * decv; \
        s0d += s0v * dv;  s0e += s0v * ev; \
        kd = fmaf(mv * encv, dv, kd); \
        ke = fmaf(mv * encv, ev, ke); \
    } \
} while (0)

// One channel pair: pk_mul + pk_fma (tt), 2x med3, 3x pk_fma (accumulate).
#define ACC_J(i) do { \
    f32x2 tt = pk_fma(b2, e2_##i, pk_mul(a2, d2_##i)); \
    f32x2 mm; \
    mm.x = __builtin_amdgcn_fmed3f(tt.x, -1.0f, 1.0f); \
    mm.y = __builtin_amdgcn_fmed3f(tt.y, -1.0f, 1.0f); \
    p1 = pk_fma(mm, g1_##i, p1); \
    p2 = pk_fma(mm, g2_##i, p2); \
    po = pk_fma(mm, wo_##i, po); \
} while (0)

// First pair: accumulators initialized by pk_mul (no zero-init movs).
#define ACC_J0(i) do { \
    f32x2 tt = pk_fma(b2, e2_##i, pk_mul(a2, d2_##i)); \
    f32x2 mm; \
    mm.x = __builtin_amdgcn_fmed3f(tt.x, -1.0f, 1.0f); \
    mm.y = __builtin_amdgcn_fmed3f(tt.y, -1.0f, 1.0f); \
    p1 = pk_mul(mm, g1_##i); \
    p2 = pk_mul(mm, g2_##i); \
    po = pk_mul(mm, wo_##i); \
} while (0)

__global__ __attribute__((amdgpu_waves_per_eu(1, 1))) __launch_bounds__(64)
void twotwonet_kernel(
    const float* __restrict__ x,        // [B, T]
    const float* __restrict__ state0,   // [n]
    const float* __restrict__ mask,     // [n]
    const float* __restrict__ w,        // [2,2]
    const float* __restrict__ dec_orth, // [n]
    const float* __restrict__ enc_orth, // [n]
    const float* __restrict__ decoder,  // [n]
    const float* __restrict__ encoder,  // [n]
    float* __restrict__ out)            // [B, T]
{
    const int b    = blockIdx.x;
    const int lane = threadIdx.x;   // 0..63

    const float w00 = w[0], w01 = w[1], w10 = w[2], w11 = w[3];

    DECL_TBL(0); DECL_TBL(1); DECL_TBL(2); DECL_TBL(3);
    DECL_TBL(4); DECL_TBL(5); DECL_TBL(6); DECL_TBL(7);

    float s0d = 0.f, s0e = 0.f, kd = 0.f, ke = 0.f;
    INIT_TBL(0); INIT_TBL(1); INIT_TBL(2); INIT_TBL(3);
    INIT_TBL(4); INIT_TBL(5); INIT_TBL(6); INIT_TBL(7);

    // cold-path init reduce (runs once)
#pragma unroll
    for (int m = 32; m >= 1; m >>= 1) {
        s0d += __shfl_xor(s0d, m, 64);
        s0e += __shfl_xor(s0e, m, 64);
        kd  += __shfl_xor(kd, m, 64);
        ke  += __shfl_xor(ke, m, 64);
    }

    const float A1 = fmaf(w00, kd, w01 * ke);   // x-coupling for alpha
    const float A2 = fmaf(w10, kd, w11 * ke);   // x-coupling for beta

    // Preload this batch's entire x row: 8 regs, 64 steps each.
    const float* xrow = x + (size_t)b * Tc;
    float xr[CH];
#pragma unroll
    for (int c = 0; c < CH; ++c) xr[c] = xrow[lane + 64 * c];

    // Carried state (wave-uniform): q1 = w00*Sd + w01*Se, q2 = w10*Sd + w11*Se
    float q1 = fmaf(w00, s0d, w01 * s0e);
    float q2 = fmaf(w10, s0d, w11 * s0e);

#pragma unroll
    for (int c = 0; c < CH; ++c) {
        float obuf = 0.f;
#pragma unroll 2
        for (int t2 = 0; t2 < 64; ++t2) {
            const float xs = readlane_f(xr[c], t2);

            const float al = fmaf(xs, A1, q1);
            const float be = fmaf(xs, A2, q2);
            const f32x2 a2 = {al, al};
            const f32x2 b2 = {be, be};

            f32x2 p1, p2, po;
            ACC_J0(0);
            ACC_J(1); ACC_J(2); ACC_J(3);
            ACC_J(4); ACC_J(5); ACC_J(6); ACC_J(7);

            float h1 = p1.x + p1.y;
            float h2 = p2.x + p2.y;
            float ho = po.x + po.y;

            float r1, r2, ro;
            WAVE_REDUCE3_READ(h1, h2, ho, r1, r2, ro);
            q1 = r1;                        // = w00*Sd' + w01*Se'
            q2 = r2;

            obuf = (t2 == lane) ? ro : obuf;
        }
        out[(size_t)b * Tc + 64 * c + lane] = obuf;
    }
}

extern "C" void kernel_launch(void* const* d_in, const int* in_sizes, int n_in,
                              void* d_out, int out_size, void* d_ws, size_t ws_size,
                              hipStream_t stream) {
    const float* x        = (const float*)d_in[0];
    const float* state0   = (const float*)d_in[1];
    const float* mask     = (const float*)d_in[2];
    const float* w        = (const float*)d_in[3];
    const float* dec_orth = (const float*)d_in[4];
    const float* enc_orth = (const float*)d_in[5];
    const float* decoder  = (const float*)d_in[6];
    const float* encoder  = (const float*)d_in[7];
    float* out = (float*)d_out;

    twotwonet_kernel<<<dim3(Bc), dim3(64), 0, stream>>>(
        x, state0, mask, w, dec_orth, enc_orth, decoder, encoder, out);
}